// Round 6
// baseline (180.693 us; speedup 1.0000x reference)
//
#include <hip/hip_runtime.h>
#include <hip/hip_bf16.h>

// Problem constants: B=2, S=4096, E=512, H=8, D=64
typedef __attribute__((ext_vector_type(8))) short bf16x8;
typedef __attribute__((ext_vector_type(4))) float f32x4;

#define MFMA16 __builtin_amdgcn_mfma_f32_16x16x32_bf16

__device__ __forceinline__ unsigned short f2bf(float f) {
  unsigned int u = __builtin_bit_cast(unsigned int, f);
  u += 0x7FFFu + ((u >> 16) & 1u);   // round-to-nearest-even
  return (unsigned short)(u >> 16);
}

__device__ __forceinline__ void load_lds16(const void* g, void* l) {
  __builtin_amdgcn_global_load_lds(
      (const __attribute__((address_space(1))) unsigned int*)g,
      (__attribute__((address_space(3))) unsigned int*)l, 16, 0, 0);
}

// ---------------------------------------------------------------------------
// Prep: x -> bf16 (row-major [8192][512]); w_qkv -> bf16 transposed [1536][512];
// w_out -> bf16 transposed [512][512].
// ---------------------------------------------------------------------------
__global__ __launch_bounds__(256) void prep_kernel(
    const float* __restrict__ x, const float* __restrict__ wqkv,
    const float* __restrict__ wout, unsigned short* __restrict__ xb,
    unsigned short* __restrict__ wqkvT, unsigned short* __restrict__ woutT) {
  int blk = blockIdx.x;
  int t = threadIdx.x;
  if (blk < 4096) {                       // x convert: 4,194,304 elems
    int i = (blk * 256 + t) * 4;
    float4 v = *(const float4*)(x + i);
    ushort4 o;
    o.x = f2bf(v.x); o.y = f2bf(v.y); o.z = f2bf(v.z); o.w = f2bf(v.w);
    *(ushort4*)(xb + i) = o;
  } else if (blk < 4864) {                // w_qkv transpose: 512 x 1536
    int u = ((blk - 4096) * 256 + t) * 4;
    int k = u / 1536, n = u % 1536;
    float4 v = *(const float4*)(wqkv + (size_t)k * 1536 + n);
    wqkvT[(size_t)(n + 0) * 512 + k] = f2bf(v.x);
    wqkvT[(size_t)(n + 1) * 512 + k] = f2bf(v.y);
    wqkvT[(size_t)(n + 2) * 512 + k] = f2bf(v.z);
    wqkvT[(size_t)(n + 3) * 512 + k] = f2bf(v.w);
  } else {                                // w_out transpose: 512 x 512
    int u = ((blk - 4864) * 256 + t) * 4;
    int k = u >> 9, n = u & 511;
    float4 v = *(const float4*)(wout + (size_t)k * 512 + n);
    woutT[(size_t)(n + 0) * 512 + k] = f2bf(v.x);
    woutT[(size_t)(n + 1) * 512 + k] = f2bf(v.y);
    woutT[(size_t)(n + 2) * 512 + k] = f2bf(v.z);
    woutT[(size_t)(n + 3) * 512 + k] = f2bf(v.w);
  }
}

// ---------------------------------------------------------------------------
// QKV GEMM: C[8192][1536] = xb[8192][512] @ wqkvT^T + b_qkv
// Epilogue scatters: q [bh][s][d] (scaled by D^-0.5 * log2(e) for exp2-softmax),
// K swizzled tiles (LDS-staged in attn), V^T tiles with key-PERMUTED columns,
// UNswizzled (attn reads V global->register, no LDS banks involved).
// ---------------------------------------------------------------------------
__global__ __launch_bounds__(256, 2) void qkv_gemm(
    const unsigned short* __restrict__ xb, const unsigned short* __restrict__ bt,
    const float* __restrict__ bias, unsigned short* __restrict__ qout,
    unsigned short* __restrict__ ksw, unsigned short* __restrict__ vtsw) {
  __shared__ unsigned short As[128 * 32];
  __shared__ unsigned short Bs[128 * 32];
  const int t = threadIdx.x;
  const int lane = t & 63;
  const int llo = lane & 15, lhi = lane >> 4;
  const int w = t >> 6, wr = w >> 1, wc = w & 1;
  const int m0 = blockIdx.x * 128, n0 = blockIdx.y * 128;

  f32x4 acc[4][4];
#pragma unroll
  for (int i = 0; i < 4; ++i)
#pragma unroll
    for (int j = 0; j < 4; ++j) acc[i][j] = (f32x4){0.f, 0.f, 0.f, 0.f};

  const int r0 = t >> 2;            // staging row (unit t)
  const int sb = (t & 3) * 16;      // byte seg within row (64B rows)

  for (int k0 = 0; k0 < 512; k0 += 32) {
    const char* ga = (const char*)xb + (size_t)(m0 + r0) * 1024 + k0 * 2 + sb;
    const char* gb = (const char*)bt + (size_t)(n0 + r0) * 1024 + k0 * 2 + sb;
    load_lds16(ga, (char*)As + t * 16);
    load_lds16(ga + 64 * 1024, (char*)As + 4096 + t * 16);
    load_lds16(gb, (char*)Bs + t * 16);
    load_lds16(gb + 64 * 1024, (char*)Bs + 4096 + t * 16);
    __syncthreads();

    bf16x8 af[4], bf[4];
#pragma unroll
    for (int mi = 0; mi < 4; ++mi)
      af[mi] = *(const bf16x8*)(As + (wr * 64 + mi * 16 + llo) * 32 + lhi * 8);
#pragma unroll
    for (int ni = 0; ni < 4; ++ni)
      bf[ni] = *(const bf16x8*)(Bs + (wc * 64 + ni * 16 + llo) * 32 + lhi * 8);
#pragma unroll
    for (int mi = 0; mi < 4; ++mi)
#pragma unroll
      for (int ni = 0; ni < 4; ++ni)
        acc[mi][ni] = MFMA16(af[mi], bf[ni], acc[mi][ni], 0, 0, 0);
    __syncthreads();
  }

  // Epilogue: section uniform per block (n-tile of 128 within one 512 section)
#pragma unroll
  for (int ni = 0; ni < 4; ++ni) {
    int col = n0 + wc * 64 + ni * 16 + llo;
    float bv = bias[col];
    int sec = col >> 9;
    int h = (col >> 6) & 7;
    int d = col & 63;
#pragma unroll
    for (int mi = 0; mi < 4; ++mi) {
      int rowb = m0 + wr * 64 + mi * 16 + lhi * 4;
#pragma unroll
      for (int r = 0; r < 4; ++r) {
        int m = rowb + r;
        int b = m >> 12, s = m & 4095;
        int bh = (b << 3) + h;
        float val = acc[mi][ni][r] + bv;
        if (sec == 0) {
          // q scale: D^-0.5 * log2(e) = 0.125 * 1.4426950408889634
          qout[((size_t)bh * 4096 + s) * 64 + d] = f2bf(val * 0.18033688f);
        } else if (sec == 1) {
          // K swizzled tiles: [bh][s/64][s%64 row][ (d*2) ^ ((s&7)<<4) ]
          size_t byte = (size_t)bh * 524288 + (size_t)(s >> 6) * 8192 +
                        (size_t)(s & 63) * 128 + ((d * 2) ^ ((s & 7) << 4));
          *(unsigned short*)((char*)ksw + byte) = f2bf(val);
        } else {
          // V^T tiles, key-permuted columns, UNswizzled:
          // orig key u64k = c*16 + u  ->  kperm = (c>>1)*32 + (u>>2)*8 + (c&1)*4 + (u&3)
          // so that PV's A-fragment (P) slot (f,lhi,j) = lane's own e[2f+(j>>2)][j&3].
          int u64k = s & 63;
          int c = u64k >> 4, u = u64k & 15;
          int kperm = ((c >> 1) << 5) + ((u >> 2) << 3) + ((c & 1) << 2) + (u & 3);
          size_t byte = (size_t)bh * 524288 + (size_t)(s >> 6) * 8192 +
                        (size_t)d * 128 + kperm * 2;
          *(unsigned short*)((char*)vtsw + byte) = f2bf(val);
        }
      }
    }
  }
}

// ---------------------------------------------------------------------------
// Flash attention, round 6 (= round 5 pipeline, V moved global->register):
//  - V fragments loaded directly from L2/L1 into double-buffered register
//    arrays (vA/vB), issued one tile ahead; LDS holds only K (16 KB dbuf).
//    Halves LDS port traffic, removes V's lgkm chain before PV; the per-tile
//    __syncthreads vmcnt(0) drain lands the prefetched loads for free.
//  - per iteration t: QK^T(t+1) [MFMA] || softmax(t) [VALU] || PV(t) [MFMA]
//    with scores in named scA/scB, loop unrolled x2 (all static indexing).
// ---------------------------------------------------------------------------
__global__ __launch_bounds__(256, 2) void attn_kernel(
    const unsigned short* __restrict__ qp, const unsigned short* __restrict__ ksw,
    const unsigned short* __restrict__ vtsw, unsigned short* __restrict__ aout) {
  __shared__ unsigned short Ks[2][4096];     // [buf][64 key][64 d] swizzled

  const int t = threadIdx.x, lane = t & 63, w = t >> 6;
  const int llo = lane & 15, lhi = lane >> 4;

  // XCD swizzle: 512 blocks, 8 XCDs, 64 blocks per XCD = 2 bh each
  const int wg = blockIdx.x + (blockIdx.y << 5);
  const int pidx = ((wg & 7) << 6) + (wg >> 3);
  const int bh = pidx >> 5;
  const int q0 = (pidx & 31) * 128 + w * 32;

  // Q fragments (q pre-scaled by D^-0.5*log2e in qkv_gemm); B-operand layout
  bf16x8 qf[2][2];
#pragma unroll
  for (int qs = 0; qs < 2; ++qs)
#pragma unroll
    for (int f = 0; f < 2; ++f) {
      int row = q0 + qs * 16 + llo;
      int d = f * 32 + lhi * 8;
      qf[qs][f] = *(const bf16x8*)(qp + ((size_t)bh * 4096 + row) * 64 + d);
    }

  float lpart[2] = {0.f, 0.f};
  f32x4 o[2][4];
#pragma unroll
  for (int qs = 0; qs < 2; ++qs)
#pragma unroll
    for (int di = 0; di < 4; ++di) o[qs][di] = (f32x4){0.f, 0.f, 0.f, 0.f};

  const char* kbase = (const char*)ksw + (size_t)bh * 524288;
  const char* vbase = (const char*)vtsw + (size_t)bh * 524288;
  // per-lane V fragment base within a tile: row d = di*16+llo, cols lhi*8+f*32
  const char* vlane = vbase + llo * 128 + lhi * 16;

  bf16x8 pf[2][2];
  bf16x8 vA[8], vB[8];    // V fragments, index f*4+di; double-buffered

  auto stage_k = [&](int kt, char* d) {
    const char* g = kbase + (size_t)kt * 8192;
    load_lds16(g + t * 16, d + t * 16);
    load_lds16(g + 4096 + t * 16, d + 4096 + t * 16);
  };

  auto vload = [&](bf16x8 (&vr)[8], int kt) {
    const char* vt = vlane + (size_t)kt * 8192;
#pragma unroll
    for (int f = 0; f < 2; ++f)
#pragma unroll
      for (int di = 0; di < 4; ++di)
        vr[f * 4 + di] = *(const bf16x8*)(vt + di * 2048 + f * 64);
  };

  auto qkt = [&](f32x4 (&sc)[2][4], const char* kbuf) {
    __builtin_amdgcn_s_setprio(1);
#pragma unroll
    for (int c = 0; c < 4; ++c) {
      int krow = c * 16 + llo;
      int sw = (krow & 7) << 4;
      bf16x8 kf0 = *(const bf16x8*)(kbuf + krow * 128 + ((lhi * 16) ^ sw));
      bf16x8 kf1 = *(const bf16x8*)(kbuf + krow * 128 + ((lhi * 16 + 64) ^ sw));
#pragma unroll
      for (int qs = 0; qs < 2; ++qs) {
        sc[qs][c] = MFMA16(kf0, qf[qs][0], (f32x4){0.f, 0.f, 0.f, 0.f}, 0, 0, 0);
        sc[qs][c] = MFMA16(kf1, qf[qs][1], sc[qs][c], 0, 0, 0);
      }
    }
    __builtin_amdgcn_s_setprio(0);
  };

  auto softmax_pack = [&](f32x4 (&sc)[2][4]) {
#pragma unroll
    for (int qs = 0; qs < 2; ++qs) {
      float e[4][4];
#pragma unroll
      for (int c = 0; c < 4; ++c)
#pragma unroll
        for (int r = 0; r < 4; ++r) {
          e[c][r] = __builtin_amdgcn_exp2f(sc[qs][c][r]);
          lpart[qs] += e[c][r];
        }
#pragma unroll
      for (int f = 0; f < 2; ++f) {
        bf16x8 pvv;
#pragma unroll
        for (int j = 0; j < 8; ++j)
          pvv[j] = __builtin_bit_cast(short,
                       __float2bfloat16(e[2 * f + (j >> 2)][j & 3]));
        pf[qs][f] = pvv;
      }
    }
  };

  auto pv_accum = [&](bf16x8 (&vr)[8]) {
    __builtin_amdgcn_s_setprio(1);
#pragma unroll
    for (int f = 0; f < 2; ++f)
#pragma unroll
      for (int di = 0; di < 4; ++di) {
        bf16x8 vf = vr[f * 4 + di];
#pragma unroll
        for (int qs = 0; qs < 2; ++qs)
          o[qs][di] = MFMA16(pf[qs][f], vf, o[qs][di], 0, 0, 0);
      }
    __builtin_amdgcn_s_setprio(0);
  };

  // prologue: K(0)->Ks[0], K(1)->Ks[1], V(0)->vA; then scores(0)
  stage_k(0, (char*)&Ks[0][0]);
  stage_k(1, (char*)&Ks[1][0]);
  vload(vA, 0);
  __syncthreads();

  f32x4 scA[2][4], scB[2][4];
  qkt(scA, (const char*)&Ks[0][0]);
  __syncthreads();   // all waves done reading Ks[0] before it is overwritten

  // main loop: tiles 0..61, two per iteration (kt even)
  for (int kt = 0; kt < 62; kt += 2) {
    // tile kt: cur scores=scA, cur V=vA
    stage_k(kt + 2, (char*)&Ks[0][0]);
    vload(vB, kt + 1);
    qkt(scB, (const char*)&Ks[1][0]);          // K(kt+1)
    softmax_pack(scA);                         // tile kt
    pv_accum(vA);                              // V(kt)
    __syncthreads();
    // tile kt+1: cur scores=scB, cur V=vB
    stage_k(kt + 3, (char*)&Ks[1][0]);
    vload(vA, kt + 2);
    qkt(scA, (const char*)&Ks[0][0]);          // K(kt+2)
    softmax_pack(scB);                         // tile kt+1
    pv_accum(vB);                              // V(kt+1)
    __syncthreads();
  }

  // tail: tile 62 (scA, vA holds V(62)); tile 63 (scB, vB)
  vload(vB, 63);
  qkt(scB, (const char*)&Ks[1][0]);            // K(63)
  softmax_pack(scA);                           // tile 62
  pv_accum(vA);                                // V(62)
  softmax_pack(scB);                           // tile 63
  pv_accum(vB);                                // V(63)

  // deferred row-sum reduce: lane holds partial for q=qs*16+llo spread across
  // the 4 lhi-lanes -> xor-reduce over lane bits 16,32, then redistribute to
  // the output layout's q = qs*16 + lhi*4 + r via one shfl.
  float linv[2][4];
#pragma unroll
  for (int qs = 0; qs < 2; ++qs) {
    float s = lpart[qs];
    s += __shfl_xor(s, 16, 64);
    s += __shfl_xor(s, 32, 64);
#pragma unroll
    for (int r = 0; r < 4; ++r)
      linv[qs][r] = 1.f / __shfl(s, lhi * 4 + r, 64);
  }

  // epilogue: attn_out bf16 [B][S][E] with E = h*64+d
  int b = bh >> 3, h = bh & 7;
#pragma unroll
  for (int qs = 0; qs < 2; ++qs)
#pragma unroll
    for (int di = 0; di < 4; ++di)
#pragma unroll
      for (int r = 0; r < 4; ++r) {
        int s = q0 + qs * 16 + lhi * 4 + r;
        int d = di * 16 + llo;
        float val = o[qs][di][r] * linv[qs][r];
        aout[((size_t)b * 4096 + s) * 512 + h * 64 + d] = f2bf(val);
      }
}

// ---------------------------------------------------------------------------
// Output GEMM: out[8192][512] = attn_out @ w_out + b_out (fp32 out)
// ---------------------------------------------------------------------------
__global__ __launch_bounds__(256, 2) void out_gemm(
    const unsigned short* __restrict__ ab, const unsigned short* __restrict__ bt,
    const float* __restrict__ bias, float* __restrict__ out) {
  __shared__ unsigned short As[128 * 32];
  __shared__ unsigned short Bs[128 * 32];
  const int t = threadIdx.x;
  const int lane = t & 63;
  const int llo = lane & 15, lhi = lane >> 4;
  const int w = t >> 6, wr = w >> 1, wc = w & 1;
  const int m0 = blockIdx.x * 128, n0 = blockIdx.y * 128;

  f32x4 acc[4][4];
#pragma unroll
  for (int i = 0; i < 4; ++i)
#pragma unroll
    for (int j = 0; j < 4; ++j) acc[i][j] = (f32x4){0.f, 0.f, 0.f, 0.f};

  const int r0 = t >> 2;
  const int sb = (t & 3) * 16;

  for (int k0 = 0; k0 < 512; k0 += 32) {
    const char* ga = (const char*)ab + (size_t)(m0 + r0) * 1024 + k0 * 2 + sb;
    const char* gb = (const char*)bt + (size_t)(n0 + r0) * 1024 + k0 * 2 + sb;
    load_lds16(ga, (char*)As + t * 16);
    load_lds16(ga + 64 * 1024, (char*)As + 4096 + t * 16);
    load_lds16(gb, (char*)Bs + t * 16);
    load_lds16(gb + 64 * 1024, (char*)Bs + 4096 + t * 16);
    __syncthreads();

    bf16x8 af[4], bf[4];
#pragma unroll
    for (int mi = 0; mi < 4; ++mi)
      af[mi] = *(const bf16x8*)(As + (wr * 64 + mi * 16 + llo) * 32 + lhi * 8);
#pragma unroll
    for (int ni = 0; ni < 4; ++ni)
      bf[ni] = *(const bf16x8*)(Bs + (wc * 64 + ni * 16 + llo) * 32 + lhi * 8);
#pragma unroll
    for (int mi = 0; mi < 4; ++mi)
#pragma unroll
      for (int ni = 0; ni < 4; ++ni)
        acc[mi][ni] = MFMA16(af[mi], bf[ni], acc[mi][ni], 0, 0, 0);
    __syncthreads();
  }

#pragma unroll
  for (int ni = 0; ni < 4; ++ni) {
    int col = n0 + wc * 64 + ni * 16 + llo;
    float bv = bias[col];
#pragma unroll
    for (int mi = 0; mi < 4; ++mi) {
      int rowb = m0 + wr * 64 + mi * 16 + lhi * 4;
#pragma unroll
      for (int r = 0; r < 4; ++r)
        out[(size_t)(rowb + r) * 512 + col] = acc[mi][ni][r] + bv;
    }
  }
}

// ---------------------------------------------------------------------------
extern "C" void kernel_launch(void* const* d_in, const int* in_sizes, int n_in,
                              void* d_out, int out_size, void* d_ws, size_t ws_size,
                              hipStream_t stream) {
  const float* x = (const float*)d_in[0];
  const float* wqkv = (const float*)d_in[1];
  const float* bqkv = (const float*)d_in[2];
  const float* wout = (const float*)d_in[3];
  const float* bout = (const float*)d_in[4];
  float* out = (float*)d_out;

  char* ws = (char*)d_ws;
  unsigned short* xb    = (unsigned short*)(ws + 0);         //  8,388,608 B
  unsigned short* wqkvT = (unsigned short*)(ws + 8388608);   //  1,572,864 B
  unsigned short* woutT = (unsigned short*)(ws + 9961472);   //    524,288 B
  unsigned short* qb    = (unsigned short*)(ws + 10485760);  //  8,388,608 B
  unsigned short* ksw   = (unsigned short*)(ws + 18874368);  //  8,388,608 B
  unsigned short* vtsw  = (unsigned short*)(ws + 27262976);  //  8,388,608 B
  unsigned short* ab    = (unsigned short*)(ws + 35651584);  //  8,388,608 B
  (void)ws_size; (void)in_sizes; (void)n_in; (void)out_size;

  prep_kernel<<<5120, 256, 0, stream>>>(x, wqkv, wout, xb, wqkvT, woutT);
  qkv_gemm<<<dim3(64, 12), 256, 0, stream>>>(xb, wqkvT, bqkv, qb, ksw, vtsw);
  attn_kernel<<<dim3(32, 16), 256, 0, stream>>>(qb, ksw, vtsw, ab);
  out_gemm<<<dim3(64, 4), 256, 0, stream>>>(ab, woutT, bout, out);
}

// Round 7
// 131.688 us; speedup vs baseline: 1.3721x; 1.3721x over previous
//
#include <hip/hip_runtime.h>
#include <hip/hip_bf16.h>

// Problem constants: B=2, S=4096, E=512, H=8, D=64
typedef __attribute__((ext_vector_type(8))) short bf16x8;
typedef __attribute__((ext_vector_type(4))) float f32x4;

#define MFMA16 __builtin_amdgcn_mfma_f32_16x16x32_bf16

__device__ __forceinline__ unsigned short f2bf(float f) {
  unsigned int u = __builtin_bit_cast(unsigned int, f);
  u += 0x7FFFu + ((u >> 16) & 1u);   // round-to-nearest-even
  return (unsigned short)(u >> 16);
}

__device__ __forceinline__ void load_lds16(const void* g, void* l) {
  __builtin_amdgcn_global_load_lds(
      (const __attribute__((address_space(1))) unsigned int*)g,
      (__attribute__((address_space(3))) unsigned int*)l, 16, 0, 0);
}

// ---------------------------------------------------------------------------
// Prep: x -> bf16 (row-major [8192][512]); w_qkv -> bf16 transposed [1536][512];
// w_out -> bf16 transposed [512][512].
// ---------------------------------------------------------------------------
__global__ __launch_bounds__(256) void prep_kernel(
    const float* __restrict__ x, const float* __restrict__ wqkv,
    const float* __restrict__ wout, unsigned short* __restrict__ xb,
    unsigned short* __restrict__ wqkvT, unsigned short* __restrict__ woutT) {
  int blk = blockIdx.x;
  int t = threadIdx.x;
  if (blk < 4096) {                       // x convert: 4,194,304 elems
    int i = (blk * 256 + t) * 4;
    float4 v = *(const float4*)(x + i);
    ushort4 o;
    o.x = f2bf(v.x); o.y = f2bf(v.y); o.z = f2bf(v.z); o.w = f2bf(v.w);
    *(ushort4*)(xb + i) = o;
  } else if (blk < 4864) {                // w_qkv transpose: 512 x 1536
    int u = ((blk - 4096) * 256 + t) * 4;
    int k = u / 1536, n = u % 1536;
    float4 v = *(const float4*)(wqkv + (size_t)k * 1536 + n);
    wqkvT[(size_t)(n + 0) * 512 + k] = f2bf(v.x);
    wqkvT[(size_t)(n + 1) * 512 + k] = f2bf(v.y);
    wqkvT[(size_t)(n + 2) * 512 + k] = f2bf(v.z);
    wqkvT[(size_t)(n + 3) * 512 + k] = f2bf(v.w);
  } else {                                // w_out transpose: 512 x 512
    int u = ((blk - 4864) * 256 + t) * 4;
    int k = u >> 9, n = u & 511;
    float4 v = *(const float4*)(wout + (size_t)k * 512 + n);
    woutT[(size_t)(n + 0) * 512 + k] = f2bf(v.x);
    woutT[(size_t)(n + 1) * 512 + k] = f2bf(v.y);
    woutT[(size_t)(n + 2) * 512 + k] = f2bf(v.z);
    woutT[(size_t)(n + 3) * 512 + k] = f2bf(v.w);
  }
}

// ---------------------------------------------------------------------------
// QKV GEMM: C[8192][1536] = xb[8192][512] @ wqkvT^T + b_qkv
// 2-phase double-buffered staging (stage k0+1 before computing k0).
// Epilogue scatters: q [bh][s][d] (scaled by D^-0.5 * log2(e)), K swizzled
// tiles, V^T swizzled tiles with key-PERMUTED columns (zero-shuffle PV).
// ---------------------------------------------------------------------------
__global__ __launch_bounds__(256, 2) void qkv_gemm(
    const unsigned short* __restrict__ xb, const unsigned short* __restrict__ bt,
    const float* __restrict__ bias, unsigned short* __restrict__ qout,
    unsigned short* __restrict__ ksw, unsigned short* __restrict__ vtsw) {
  __shared__ unsigned short As[2][128 * 32];
  __shared__ unsigned short Bs[2][128 * 32];
  const int t = threadIdx.x;
  const int lane = t & 63;
  const int llo = lane & 15, lhi = lane >> 4;
  const int w = t >> 6, wr = w >> 1, wc = w & 1;
  const int m0 = blockIdx.x * 128, n0 = blockIdx.y * 128;

  f32x4 acc[4][4];
#pragma unroll
  for (int i = 0; i < 4; ++i)
#pragma unroll
    for (int j = 0; j < 4; ++j) acc[i][j] = (f32x4){0.f, 0.f, 0.f, 0.f};

  const int r0 = t >> 2;            // staging row (unit t)
  const int sb = (t & 3) * 16;      // byte seg within row (64B rows)

  auto stage = [&](int k0, int buf) {
    const char* ga = (const char*)xb + (size_t)(m0 + r0) * 1024 + k0 * 2 + sb;
    const char* gb = (const char*)bt + (size_t)(n0 + r0) * 1024 + k0 * 2 + sb;
    load_lds16(ga, (char*)&As[buf][0] + t * 16);
    load_lds16(ga + 64 * 1024, (char*)&As[buf][0] + 4096 + t * 16);
    load_lds16(gb, (char*)&Bs[buf][0] + t * 16);
    load_lds16(gb + 64 * 1024, (char*)&Bs[buf][0] + 4096 + t * 16);
  };

  stage(0, 0);
  __syncthreads();

  int cur = 0;
  for (int k0 = 0; k0 < 512; k0 += 32) {
    if (k0 + 32 < 512) stage(k0 + 32, cur ^ 1);

    bf16x8 af[4], bf[4];
#pragma unroll
    for (int mi = 0; mi < 4; ++mi)
      af[mi] = *(const bf16x8*)(&As[cur][0] + (wr * 64 + mi * 16 + llo) * 32 + lhi * 8);
#pragma unroll
    for (int ni = 0; ni < 4; ++ni)
      bf[ni] = *(const bf16x8*)(&Bs[cur][0] + (wc * 64 + ni * 16 + llo) * 32 + lhi * 8);
#pragma unroll
    for (int mi = 0; mi < 4; ++mi)
#pragma unroll
      for (int ni = 0; ni < 4; ++ni)
        acc[mi][ni] = MFMA16(af[mi], bf[ni], acc[mi][ni], 0, 0, 0);
    __syncthreads();   // drains staging (vmcnt) + compute reads; next buf ready
    cur ^= 1;
  }

  // Epilogue: section uniform per block (n-tile of 128 within one 512 section)
#pragma unroll
  for (int ni = 0; ni < 4; ++ni) {
    int col = n0 + wc * 64 + ni * 16 + llo;
    float bv = bias[col];
    int sec = col >> 9;
    int h = (col >> 6) & 7;
    int d = col & 63;
#pragma unroll
    for (int mi = 0; mi < 4; ++mi) {
      int rowb = m0 + wr * 64 + mi * 16 + lhi * 4;
#pragma unroll
      for (int r = 0; r < 4; ++r) {
        int m = rowb + r;
        int b = m >> 12, s = m & 4095;
        int bh = (b << 3) + h;
        float val = acc[mi][ni][r] + bv;
        if (sec == 0) {
          // q scale: D^-0.5 * log2(e) = 0.125 * 1.4426950408889634
          qout[((size_t)bh * 4096 + s) * 64 + d] = f2bf(val * 0.18033688f);
        } else if (sec == 1) {
          // K swizzled tiles: [bh][s/64][s%64 row][ (d*2) ^ ((s&7)<<4) ]
          size_t byte = (size_t)bh * 524288 + (size_t)(s >> 6) * 8192 +
                        (size_t)(s & 63) * 128 + ((d * 2) ^ ((s & 7) << 4));
          *(unsigned short*)((char*)ksw + byte) = f2bf(val);
        } else {
          // V^T swizzled tiles with key-permuted columns:
          // orig key u64k = c*16 + u  ->  kperm = (c>>1)*32 + (u>>2)*8 + (c&1)*4 + (u&3)
          // so that PV's A-fragment (P) slot (f,lhi,j) = lane's own e[2f+(j>>2)][j&3].
          int u64k = s & 63;
          int c = u64k >> 4, u = u64k & 15;
          int kperm = ((c >> 1) << 5) + ((u >> 2) << 3) + ((c & 1) << 2) + (u & 3);
          size_t byte = (size_t)bh * 524288 + (size_t)(s >> 6) * 8192 +
                        (size_t)d * 128 + ((kperm * 2) ^ ((d & 7) << 4));
          *(unsigned short*)((char*)vtsw + byte) = f2bf(val);
        }
      }
    }
  }
}

// ---------------------------------------------------------------------------
// Flash attention (round-5 kernel, verified at 87.5 us):
//  per iteration t:  QK^T(t+1) [MFMA]  ||  softmax(t) [VALU]  ||  PV(t) [MFMA]
//  Scores in two named register arrays (scA/scB), loop unrolled x2. K(t) in
//  Ks[t&1], V(t) in Vts[t&1]; every LDS read >=1 barrier after its staging,
//  every overwrite >=1 barrier after the last read.
// ---------------------------------------------------------------------------
__global__ __launch_bounds__(256, 2) void attn_kernel(
    const unsigned short* __restrict__ qp, const unsigned short* __restrict__ ksw,
    const unsigned short* __restrict__ vtsw, unsigned short* __restrict__ aout) {
  __shared__ unsigned short Ks[2][4096];     // [buf][64 key][64 d] swizzled
  __shared__ unsigned short Vts[2][4096];    // [buf][64 d][64 kperm] swizzled

  const int t = threadIdx.x, lane = t & 63, w = t >> 6;
  const int llo = lane & 15, lhi = lane >> 4;

  // XCD swizzle: 512 blocks, 8 XCDs, 64 blocks per XCD = 2 bh each
  const int wg = blockIdx.x + (blockIdx.y << 5);
  const int pidx = ((wg & 7) << 6) + (wg >> 3);
  const int bh = pidx >> 5;
  const int q0 = (pidx & 31) * 128 + w * 32;

  // Q fragments (q pre-scaled by D^-0.5*log2e in qkv_gemm); B-operand layout
  bf16x8 qf[2][2];
#pragma unroll
  for (int qs = 0; qs < 2; ++qs)
#pragma unroll
    for (int f = 0; f < 2; ++f) {
      int row = q0 + qs * 16 + llo;
      int d = f * 32 + lhi * 8;
      qf[qs][f] = *(const bf16x8*)(qp + ((size_t)bh * 4096 + row) * 64 + d);
    }

  float lpart[2] = {0.f, 0.f};
  f32x4 o[2][4];
#pragma unroll
  for (int qs = 0; qs < 2; ++qs)
#pragma unroll
    for (int di = 0; di < 4; ++di) o[qs][di] = (f32x4){0.f, 0.f, 0.f, 0.f};

  const char* kbase = (const char*)ksw + (size_t)bh * 524288;
  const char* vbase = (const char*)vtsw + (size_t)bh * 524288;

  bf16x8 pf[2][2];

  auto stage_tile = [&](const char* g, char* d) {
    load_lds16(g + t * 16, d + t * 16);
    load_lds16(g + 4096 + t * 16, d + 4096 + t * 16);
  };

  auto qkt = [&](f32x4 (&sc)[2][4], const char* kbuf) {
    __builtin_amdgcn_s_setprio(1);
#pragma unroll
    for (int c = 0; c < 4; ++c) {
      int krow = c * 16 + llo;
      int sw = (krow & 7) << 4;
      bf16x8 kf0 = *(const bf16x8*)(kbuf + krow * 128 + ((lhi * 16) ^ sw));
      bf16x8 kf1 = *(const bf16x8*)(kbuf + krow * 128 + ((lhi * 16 + 64) ^ sw));
#pragma unroll
      for (int qs = 0; qs < 2; ++qs) {
        sc[qs][c] = MFMA16(kf0, qf[qs][0], (f32x4){0.f, 0.f, 0.f, 0.f}, 0, 0, 0);
        sc[qs][c] = MFMA16(kf1, qf[qs][1], sc[qs][c], 0, 0, 0);
      }
    }
    __builtin_amdgcn_s_setprio(0);
  };

  auto softmax_pack = [&](f32x4 (&sc)[2][4]) {
#pragma unroll
    for (int qs = 0; qs < 2; ++qs) {
      float e[4][4];
#pragma unroll
      for (int c = 0; c < 4; ++c)
#pragma unroll
        for (int r = 0; r < 4; ++r) {
          e[c][r] = __builtin_amdgcn_exp2f(sc[qs][c][r]);
          lpart[qs] += e[c][r];
        }
#pragma unroll
      for (int f = 0; f < 2; ++f) {
        bf16x8 pvv;
#pragma unroll
        for (int j = 0; j < 8; ++j)
          pvv[j] = __builtin_bit_cast(short,
                       __float2bfloat16(e[2 * f + (j >> 2)][j & 3]));
        pf[qs][f] = pvv;
      }
    }
  };

  auto pv_accum = [&](const char* vbuf) {
    __builtin_amdgcn_s_setprio(1);
#pragma unroll
    for (int f = 0; f < 2; ++f)
#pragma unroll
      for (int di = 0; di < 4; ++di) {
        int vrow = di * 16 + llo;
        int byte = vrow * 128 + ((lhi * 16 + f * 64) ^ ((vrow & 7) << 4));
        bf16x8 vf = *(const bf16x8*)(vbuf + byte);
#pragma unroll
        for (int qs = 0; qs < 2; ++qs)
          o[qs][di] = MFMA16(pf[qs][f], vf, o[qs][di], 0, 0, 0);
      }
    __builtin_amdgcn_s_setprio(0);
  };

  // prologue: K(0)->Ks[0], V(0)->Vts[0], K(1)->Ks[1]; then scores(0)
  stage_tile(kbase, (char*)&Ks[0][0]);
  stage_tile(vbase, (char*)&Vts[0][0]);
  stage_tile(kbase + 8192, (char*)&Ks[1][0]);
  __syncthreads();

  f32x4 scA[2][4], scB[2][4];
  qkt(scA, (const char*)&Ks[0][0]);
  __syncthreads();   // all waves done reading Ks[0] before it is overwritten

  // main loop: tiles 0..61, two per iteration (kt even)
  for (int kt = 0; kt < 62; kt += 2) {
    // tile kt (bcur=0): cur=scA, next=scB
    stage_tile(kbase + (size_t)(kt + 2) * 8192, (char*)&Ks[0][0]);
    stage_tile(vbase + (size_t)(kt + 1) * 8192, (char*)&Vts[1][0]);
    qkt(scB, (const char*)&Ks[1][0]);          // K(kt+1)
    softmax_pack(scA);                         // tile kt
    pv_accum((const char*)&Vts[0][0]);         // V(kt)
    __syncthreads();
    // tile kt+1 (bcur=1): cur=scB, next=scA
    stage_tile(kbase + (size_t)(kt + 3) * 8192, (char*)&Ks[1][0]);
    stage_tile(vbase + (size_t)(kt + 2) * 8192, (char*)&Vts[0][0]);
    qkt(scA, (const char*)&Ks[0][0]);          // K(kt+2)
    softmax_pack(scB);                         // tile kt+1
    pv_accum((const char*)&Vts[1][0]);         // V(kt+1)
    __syncthreads();
  }

  // tail: tile 62 (bcur=0)
  stage_tile(vbase + (size_t)63 * 8192, (char*)&Vts[1][0]);
  qkt(scB, (const char*)&Ks[1][0]);            // K(63), staged at kt=60 odd half
  softmax_pack(scA);                           // tile 62
  pv_accum((const char*)&Vts[0][0]);           // V(62)
  __syncthreads();
  // tail: tile 63 (bcur=1)
  softmax_pack(scB);                           // tile 63
  pv_accum((const char*)&Vts[1][0]);           // V(63)

  // deferred row-sum reduce: lane holds partial for q=qs*16+llo spread across
  // the 4 lhi-lanes -> xor-reduce over lane bits 16,32, then redistribute to
  // the output layout's q = qs*16 + lhi*4 + r via one shfl.
  float linv[2][4];
#pragma unroll
  for (int qs = 0; qs < 2; ++qs) {
    float s = lpart[qs];
    s += __shfl_xor(s, 16, 64);
    s += __shfl_xor(s, 32, 64);
#pragma unroll
    for (int r = 0; r < 4; ++r)
      linv[qs][r] = 1.f / __shfl(s, lhi * 4 + r, 64);
  }

  // epilogue: attn_out bf16 [B][S][E] with E = h*64+d
  int b = bh >> 3, h = bh & 7;
#pragma unroll
  for (int qs = 0; qs < 2; ++qs)
#pragma unroll
    for (int di = 0; di < 4; ++di)
#pragma unroll
      for (int r = 0; r < 4; ++r) {
        int s = q0 + qs * 16 + lhi * 4 + r;
        int d = di * 16 + llo;
        float val = o[qs][di][r] * linv[qs][r];
        aout[((size_t)b * 4096 + s) * 512 + h * 64 + d] = f2bf(val);
      }
}

// ---------------------------------------------------------------------------
// Output GEMM: out[8192][512] = attn_out @ w_out + b_out (fp32 out)
// 2-phase double-buffered staging.
// ---------------------------------------------------------------------------
__global__ __launch_bounds__(256, 2) void out_gemm(
    const unsigned short* __restrict__ ab, const unsigned short* __restrict__ bt,
    const float* __restrict__ bias, float* __restrict__ out) {
  __shared__ unsigned short As[2][128 * 32];
  __shared__ unsigned short Bs[2][128 * 32];
  const int t = threadIdx.x;
  const int lane = t & 63;
  const int llo = lane & 15, lhi = lane >> 4;
  const int w = t >> 6, wr = w >> 1, wc = w & 1;
  const int m0 = blockIdx.x * 128, n0 = blockIdx.y * 128;

  f32x4 acc[4][4];
#pragma unroll
  for (int i = 0; i < 4; ++i)
#pragma unroll
    for (int j = 0; j < 4; ++j) acc[i][j] = (f32x4){0.f, 0.f, 0.f, 0.f};

  const int r0 = t >> 2;
  const int sb = (t & 3) * 16;

  auto stage = [&](int k0, int buf) {
    const char* ga = (const char*)ab + (size_t)(m0 + r0) * 1024 + k0 * 2 + sb;
    const char* gb = (const char*)bt + (size_t)(n0 + r0) * 1024 + k0 * 2 + sb;
    load_lds16(ga, (char*)&As[buf][0] + t * 16);
    load_lds16(ga + 64 * 1024, (char*)&As[buf][0] + 4096 + t * 16);
    load_lds16(gb, (char*)&Bs[buf][0] + t * 16);
    load_lds16(gb + 64 * 1024, (char*)&Bs[buf][0] + 4096 + t * 16);
  };

  stage(0, 0);
  __syncthreads();

  int cur = 0;
  for (int k0 = 0; k0 < 512; k0 += 32) {
    if (k0 + 32 < 512) stage(k0 + 32, cur ^ 1);

    bf16x8 af[4], bf[4];
#pragma unroll
    for (int mi = 0; mi < 4; ++mi)
      af[mi] = *(const bf16x8*)(&As[cur][0] + (wr * 64 + mi * 16 + llo) * 32 + lhi * 8);
#pragma unroll
    for (int ni = 0; ni < 4; ++ni)
      bf[ni] = *(const bf16x8*)(&Bs[cur][0] + (wc * 64 + ni * 16 + llo) * 32 + lhi * 8);
#pragma unroll
    for (int mi = 0; mi < 4; ++mi)
#pragma unroll
      for (int ni = 0; ni < 4; ++ni)
        acc[mi][ni] = MFMA16(af[mi], bf[ni], acc[mi][ni], 0, 0, 0);
    __syncthreads();
    cur ^= 1;
  }

#pragma unroll
  for (int ni = 0; ni < 4; ++ni) {
    int col = n0 + wc * 64 + ni * 16 + llo;
    float bv = bias[col];
#pragma unroll
    for (int mi = 0; mi < 4; ++mi) {
      int rowb = m0 + wr * 64 + mi * 16 + lhi * 4;
#pragma unroll
      for (int r = 0; r < 4; ++r)
        out[(size_t)(rowb + r) * 512 + col] = acc[mi][ni][r] + bv;
    }
  }
}

// ---------------------------------------------------------------------------
extern "C" void kernel_launch(void* const* d_in, const int* in_sizes, int n_in,
                              void* d_out, int out_size, void* d_ws, size_t ws_size,
                              hipStream_t stream) {
  const float* x = (const float*)d_in[0];
  const float* wqkv = (const float*)d_in[1];
  const float* bqkv = (const float*)d_in[2];
  const float* wout = (const float*)d_in[3];
  const float* bout = (const float*)d_in[4];
  float* out = (float*)d_out;

  char* ws = (char*)d_ws;
  unsigned short* xb    = (unsigned short*)(ws + 0);         //  8,388,608 B
  unsigned short* wqkvT = (unsigned short*)(ws + 8388608);   //  1,572,864 B
  unsigned short* woutT = (unsigned short*)(ws + 9961472);   //    524,288 B
  unsigned short* qb    = (unsigned short*)(ws + 10485760);  //  8,388,608 B
  unsigned short* ksw   = (unsigned short*)(ws + 18874368);  //  8,388,608 B
  unsigned short* vtsw  = (unsigned short*)(ws + 27262976);  //  8,388,608 B
  unsigned short* ab    = (unsigned short*)(ws + 35651584);  //  8,388,608 B
  (void)ws_size; (void)in_sizes; (void)n_in; (void)out_size;

  prep_kernel<<<5120, 256, 0, stream>>>(x, wqkv, wout, xb, wqkvT, woutT);
  qkv_gemm<<<dim3(64, 12), 256, 0, stream>>>(xb, wqkvT, bqkv, qb, ksw, vtsw);
  attn_kernel<<<dim3(32, 16), 256, 0, stream>>>(qb, ksw, vtsw, ab);
  out_gemm<<<dim3(64, 4), 256, 0, stream>>>(ab, woutT, bout, out);
}

// Round 8
// 129.386 us; speedup vs baseline: 1.3965x; 1.0178x over previous
//
#include <hip/hip_runtime.h>
#include <hip/hip_bf16.h>

// Problem constants: B=2, S=4096, E=512, H=8, D=64
typedef __attribute__((ext_vector_type(8))) short bf16x8;
typedef __attribute__((ext_vector_type(4))) float f32x4;

#define MFMA16 __builtin_amdgcn_mfma_f32_16x16x32_bf16

__device__ __forceinline__ unsigned short f2bf(float f) {
  unsigned int u = __builtin_bit_cast(unsigned int, f);
  u += 0x7FFFu + ((u >> 16) & 1u);   // round-to-nearest-even
  return (unsigned short)(u >> 16);
}

__device__ __forceinline__ void load_lds16(const void* g, void* l) {
  __builtin_amdgcn_global_load_lds(
      (const __attribute__((address_space(1))) unsigned int*)g,
      (__attribute__((address_space(3))) unsigned int*)l, 16, 0, 0);
}

// ---------------------------------------------------------------------------
// Prep: x -> bf16 (row-major [8192][512]); w_qkv -> bf16 transposed [1536][512];
// w_out -> bf16 transposed [512][512].
// ---------------------------------------------------------------------------
__global__ __launch_bounds__(256) void prep_kernel(
    const float* __restrict__ x, const float* __restrict__ wqkv,
    const float* __restrict__ wout, unsigned short* __restrict__ xb,
    unsigned short* __restrict__ wqkvT, unsigned short* __restrict__ woutT) {
  int blk = blockIdx.x;
  int t = threadIdx.x;
  if (blk < 4096) {                       // x convert: 4,194,304 elems
    int i = (blk * 256 + t) * 4;
    float4 v = *(const float4*)(x + i);
    ushort4 o;
    o.x = f2bf(v.x); o.y = f2bf(v.y); o.z = f2bf(v.z); o.w = f2bf(v.w);
    *(ushort4*)(xb + i) = o;
  } else if (blk < 4864) {                // w_qkv transpose: 512 x 1536
    int u = ((blk - 4096) * 256 + t) * 4;
    int k = u / 1536, n = u % 1536;
    float4 v = *(const float4*)(wqkv + (size_t)k * 1536 + n);
    wqkvT[(size_t)(n + 0) * 512 + k] = f2bf(v.x);
    wqkvT[(size_t)(n + 1) * 512 + k] = f2bf(v.y);
    wqkvT[(size_t)(n + 2) * 512 + k] = f2bf(v.z);
    wqkvT[(size_t)(n + 3) * 512 + k] = f2bf(v.w);
  } else {                                // w_out transpose: 512 x 512
    int u = ((blk - 4864) * 256 + t) * 4;
    int k = u >> 9, n = u & 511;
    float4 v = *(const float4*)(wout + (size_t)k * 512 + n);
    woutT[(size_t)(n + 0) * 512 + k] = f2bf(v.x);
    woutT[(size_t)(n + 1) * 512 + k] = f2bf(v.y);
    woutT[(size_t)(n + 2) * 512 + k] = f2bf(v.z);
    woutT[(size_t)(n + 3) * 512 + k] = f2bf(v.w);
  }
}

// ---------------------------------------------------------------------------
// QKV GEMM: C[8192][1536] = xb[8192][512] @ wqkvT^T + b_qkv
// 2-phase double-buffered staging. Epilogue via LDS transpose:
//   phase 1: scatter acc (bf16, bias/scale applied) into a 32KB LDS tile,
//            with the K-XOR / V-kperm permutations baked into LDS positions
//            (XOR (row&15)<<3 bank swizzle on the 128-u16 rows).
//   phase 2: 8 x 16B coalesced global stores per thread.
// Global layouts identical to round 7 (attn unchanged).
// ---------------------------------------------------------------------------
__global__ __launch_bounds__(256, 2) void qkv_gemm(
    const unsigned short* __restrict__ xb, const unsigned short* __restrict__ bt,
    const float* __restrict__ bias, unsigned short* __restrict__ qout,
    unsigned short* __restrict__ ksw, unsigned short* __restrict__ vtsw) {
  __shared__ unsigned short SH[16384];   // 32KB: staging dbuf, then epilogue tile
  const int t = threadIdx.x;
  const int lane = t & 63;
  const int llo = lane & 15, lhi = lane >> 4;
  const int w = t >> 6, wr = w >> 1, wc = w & 1;
  const int m0 = blockIdx.x * 128, n0 = blockIdx.y * 128;

  f32x4 acc[4][4];
#pragma unroll
  for (int i = 0; i < 4; ++i)
#pragma unroll
    for (int j = 0; j < 4; ++j) acc[i][j] = (f32x4){0.f, 0.f, 0.f, 0.f};

  const int r0 = t >> 2;            // staging row (unit t)
  const int sb = (t & 3) * 16;      // byte seg within row (64B rows)

  auto stage = [&](int k0, int buf) {
    const char* ga = (const char*)xb + (size_t)(m0 + r0) * 1024 + k0 * 2 + sb;
    const char* gb = (const char*)bt + (size_t)(n0 + r0) * 1024 + k0 * 2 + sb;
    char* la = (char*)SH + buf * 8192;
    char* lb = (char*)SH + 16384 + buf * 8192;
    load_lds16(ga, la + t * 16);
    load_lds16(ga + 64 * 1024, la + 4096 + t * 16);
    load_lds16(gb, lb + t * 16);
    load_lds16(gb + 64 * 1024, lb + 4096 + t * 16);
  };

  stage(0, 0);
  __syncthreads();

  int cur = 0;
  for (int k0 = 0; k0 < 512; k0 += 32) {
    if (k0 + 32 < 512) stage(k0 + 32, cur ^ 1);

    const unsigned short* usA = SH + cur * 4096;
    const unsigned short* usB = SH + 8192 + cur * 4096;
    bf16x8 af[4], bf[4];
#pragma unroll
    for (int mi = 0; mi < 4; ++mi)
      af[mi] = *(const bf16x8*)(usA + (wr * 64 + mi * 16 + llo) * 32 + lhi * 8);
#pragma unroll
    for (int ni = 0; ni < 4; ++ni)
      bf[ni] = *(const bf16x8*)(usB + (wc * 64 + ni * 16 + llo) * 32 + lhi * 8);
#pragma unroll
    for (int mi = 0; mi < 4; ++mi)
#pragma unroll
      for (int ni = 0; ni < 4; ++ni)
        acc[mi][ni] = MFMA16(af[mi], bf[ni], acc[mi][ni], 0, 0, 0);
    __syncthreads();   // drains staging + compute reads; next buf ready
    cur ^= 1;
  }

  // ---- epilogue phase 1: scatter into SH (layout-permuted, bank-swizzled) ----
  const int sec = n0 >> 9;               // 0=q, 1=K, 2=V (uniform per block)
  const int hbase = (n0 >> 6) & 7;
#pragma unroll
  for (int ni = 0; ni < 4; ++ni) {
    int lcol = wc * 64 + ni * 16 + llo;
    float bv = bias[n0 + lcol];
#pragma unroll
    for (int mi = 0; mi < 4; ++mi) {
#pragma unroll
      for (int r = 0; r < 4; ++r) {
        int rowm = wr * 64 + mi * 16 + lhi * 4 + r;
        float val = acc[mi][ni][r] + bv;
        unsigned short bits;
        int idx;
        if (sec == 0) {
          // q scale: D^-0.5 * log2(e)
          bits = f2bf(val * 0.18033688f);
          idx = rowm * 128 + (lcol ^ ((rowm & 15) << 3));
        } else if (sec == 1) {
          bits = f2bf(val);
          idx = rowm * 128 + (lcol ^ ((rowm & 15) << 3));
        } else {
          bits = f2bf(val);
          int u64k = rowm & 63;
          int c = u64k >> 4, u = u64k & 15;
          int kperm = ((c >> 1) << 5) + ((u >> 2) << 3) + ((c & 1) << 2) + (u & 3);
          int ktile = rowm >> 6;
          idx = lcol * 128 + ((ktile * 64 + kperm) ^ ((lcol & 15) << 3));
        }
        SH[idx] = bits;
      }
    }
  }
  __syncthreads();

  // ---- epilogue phase 2: 8 x 16B coalesced stores per thread ----
  const int b = m0 >> 12;
  if (sec == 0) {
#pragma unroll
    for (int j = 0; j < 8; ++j) {
      int cidx = j * 256 + t;
      int dc = cidx & 7, srow = (cidx >> 3) & 127, h2 = cidx >> 10;
      int bh = b * 8 + hbase + h2;
      int s = (m0 & 4095) + srow;
      bf16x8 v = *(const bf16x8*)(SH + srow * 128 +
                                  ((h2 * 64 + dc * 8) ^ ((srow & 15) << 3)));
      *(bf16x8*)(qout + ((size_t)bh * 4096 + s) * 64 + dc * 8) = v;
    }
  } else if (sec == 1) {
#pragma unroll
    for (int j = 0; j < 8; ++j) {
      int cidx = j * 256 + t;
      int dc = cidx & 7, srow = (cidx >> 3) & 127, h2 = cidx >> 10;
      int bh = b * 8 + hbase + h2;
      int s = (m0 & 4095) + srow;
      bf16x8 v = *(const bf16x8*)(SH + srow * 128 +
                                  ((h2 * 64 + dc * 8) ^ ((srow & 15) << 3)));
      size_t byte = (size_t)bh * 524288 + (size_t)(s >> 6) * 8192 +
                    (size_t)(s & 63) * 128 + ((dc * 16) ^ ((s & 7) << 4));
      *(bf16x8*)((char*)ksw + byte) = v;
    }
  } else {
#pragma unroll
    for (int j = 0; j < 8; ++j) {
      int cidx = j * 256 + t;
      int dc = cidx & 7, drow = (cidx >> 3) & 63;
      int ktile = (cidx >> 9) & 1, h2 = cidx >> 10;
      int bh = b * 8 + hbase + h2;
      int lcol = h2 * 64 + drow;
      bf16x8 v = *(const bf16x8*)(SH + lcol * 128 +
                                  ((ktile * 64 + dc * 8) ^ ((lcol & 15) << 3)));
      size_t byte = (size_t)bh * 524288 +
                    (size_t)(((m0 & 4095) >> 6) + ktile) * 8192 +
                    (size_t)drow * 128 + ((dc * 16) ^ ((drow & 7) << 4));
      *(bf16x8*)((char*)vtsw + byte) = v;
    }
  }
}

// ---------------------------------------------------------------------------
// Flash attention (round-5 kernel, verified at 87.5 us):
//  per iteration t:  QK^T(t+1) [MFMA]  ||  softmax(t) [VALU]  ||  PV(t) [MFMA]
// ---------------------------------------------------------------------------
__global__ __launch_bounds__(256, 2) void attn_kernel(
    const unsigned short* __restrict__ qp, const unsigned short* __restrict__ ksw,
    const unsigned short* __restrict__ vtsw, unsigned short* __restrict__ aout) {
  __shared__ unsigned short Ks[2][4096];     // [buf][64 key][64 d] swizzled
  __shared__ unsigned short Vts[2][4096];    // [buf][64 d][64 kperm] swizzled

  const int t = threadIdx.x, lane = t & 63, w = t >> 6;
  const int llo = lane & 15, lhi = lane >> 4;

  // XCD swizzle: 512 blocks, 8 XCDs, 64 blocks per XCD = 2 bh each
  const int wg = blockIdx.x + (blockIdx.y << 5);
  const int pidx = ((wg & 7) << 6) + (wg >> 3);
  const int bh = pidx >> 5;
  const int q0 = (pidx & 31) * 128 + w * 32;

  // Q fragments (q pre-scaled by D^-0.5*log2e in qkv_gemm); B-operand layout
  bf16x8 qf[2][2];
#pragma unroll
  for (int qs = 0; qs < 2; ++qs)
#pragma unroll
    for (int f = 0; f < 2; ++f) {
      int row = q0 + qs * 16 + llo;
      int d = f * 32 + lhi * 8;
      qf[qs][f] = *(const bf16x8*)(qp + ((size_t)bh * 4096 + row) * 64 + d);
    }

  float lpart[2] = {0.f, 0.f};
  f32x4 o[2][4];
#pragma unroll
  for (int qs = 0; qs < 2; ++qs)
#pragma unroll
    for (int di = 0; di < 4; ++di) o[qs][di] = (f32x4){0.f, 0.f, 0.f, 0.f};

  const char* kbase = (const char*)ksw + (size_t)bh * 524288;
  const char* vbase = (const char*)vtsw + (size_t)bh * 524288;

  bf16x8 pf[2][2];

  auto stage_tile = [&](const char* g, char* d) {
    load_lds16(g + t * 16, d + t * 16);
    load_lds16(g + 4096 + t * 16, d + 4096 + t * 16);
  };

  auto qkt = [&](f32x4 (&sc)[2][4], const char* kbuf) {
    __builtin_amdgcn_s_setprio(1);
#pragma unroll
    for (int c = 0; c < 4; ++c) {
      int krow = c * 16 + llo;
      int sw = (krow & 7) << 4;
      bf16x8 kf0 = *(const bf16x8*)(kbuf + krow * 128 + ((lhi * 16) ^ sw));
      bf16x8 kf1 = *(const bf16x8*)(kbuf + krow * 128 + ((lhi * 16 + 64) ^ sw));
#pragma unroll
      for (int qs = 0; qs < 2; ++qs) {
        sc[qs][c] = MFMA16(kf0, qf[qs][0], (f32x4){0.f, 0.f, 0.f, 0.f}, 0, 0, 0);
        sc[qs][c] = MFMA16(kf1, qf[qs][1], sc[qs][c], 0, 0, 0);
      }
    }
    __builtin_amdgcn_s_setprio(0);
  };

  auto softmax_pack = [&](f32x4 (&sc)[2][4]) {
#pragma unroll
    for (int qs = 0; qs < 2; ++qs) {
      float e[4][4];
#pragma unroll
      for (int c = 0; c < 4; ++c)
#pragma unroll
        for (int r = 0; r < 4; ++r) {
          e[c][r] = __builtin_amdgcn_exp2f(sc[qs][c][r]);
          lpart[qs] += e[c][r];
        }
#pragma unroll
      for (int f = 0; f < 2; ++f) {
        bf16x8 pvv;
#pragma unroll
        for (int j = 0; j < 8; ++j)
          pvv[j] = __builtin_bit_cast(short,
                       __float2bfloat16(e[2 * f + (j >> 2)][j & 3]));
        pf[qs][f] = pvv;
      }
    }
  };

  auto pv_accum = [&](const char* vbuf) {
    __builtin_amdgcn_s_setprio(1);
#pragma unroll
    for (int f = 0; f < 2; ++f)
#pragma unroll
      for (int di = 0; di < 4; ++di) {
        int vrow = di * 16 + llo;
        int byte = vrow * 128 + ((lhi * 16 + f * 64) ^ ((vrow & 7) << 4));
        bf16x8 vf = *(const bf16x8*)(vbuf + byte);
#pragma unroll
        for (int qs = 0; qs < 2; ++qs)
          o[qs][di] = MFMA16(pf[qs][f], vf, o[qs][di], 0, 0, 0);
      }
    __builtin_amdgcn_s_setprio(0);
  };

  // prologue: K(0)->Ks[0], V(0)->Vts[0], K(1)->Ks[1]; then scores(0)
  stage_tile(kbase, (char*)&Ks[0][0]);
  stage_tile(vbase, (char*)&Vts[0][0]);
  stage_tile(kbase + 8192, (char*)&Ks[1][0]);
  __syncthreads();

  f32x4 scA[2][4], scB[2][4];
  qkt(scA, (const char*)&Ks[0][0]);
  __syncthreads();   // all waves done reading Ks[0] before it is overwritten

  // main loop: tiles 0..61, two per iteration (kt even)
  for (int kt = 0; kt < 62; kt += 2) {
    // tile kt (bcur=0): cur=scA, next=scB
    stage_tile(kbase + (size_t)(kt + 2) * 8192, (char*)&Ks[0][0]);
    stage_tile(vbase + (size_t)(kt + 1) * 8192, (char*)&Vts[1][0]);
    qkt(scB, (const char*)&Ks[1][0]);          // K(kt+1)
    softmax_pack(scA);                         // tile kt
    pv_accum((const char*)&Vts[0][0]);         // V(kt)
    __syncthreads();
    // tile kt+1 (bcur=1): cur=scB, next=scA
    stage_tile(kbase + (size_t)(kt + 3) * 8192, (char*)&Ks[1][0]);
    stage_tile(vbase + (size_t)(kt + 2) * 8192, (char*)&Vts[0][0]);
    qkt(scA, (const char*)&Ks[0][0]);          // K(kt+2)
    softmax_pack(scB);                         // tile kt+1
    pv_accum((const char*)&Vts[1][0]);         // V(kt+1)
    __syncthreads();
  }

  // tail: tile 62 (bcur=0)
  stage_tile(vbase + (size_t)63 * 8192, (char*)&Vts[1][0]);
  qkt(scB, (const char*)&Ks[1][0]);            // K(63)
  softmax_pack(scA);                           // tile 62
  pv_accum((const char*)&Vts[0][0]);           // V(62)
  __syncthreads();
  // tail: tile 63 (bcur=1)
  softmax_pack(scB);                           // tile 63
  pv_accum((const char*)&Vts[1][0]);           // V(63)

  // deferred row-sum reduce
  float linv[2][4];
#pragma unroll
  for (int qs = 0; qs < 2; ++qs) {
    float s = lpart[qs];
    s += __shfl_xor(s, 16, 64);
    s += __shfl_xor(s, 32, 64);
#pragma unroll
    for (int r = 0; r < 4; ++r)
      linv[qs][r] = 1.f / __shfl(s, lhi * 4 + r, 64);
  }

  // epilogue: attn_out bf16 [B][S][E] with E = h*64+d
  int b = bh >> 3, h = bh & 7;
#pragma unroll
  for (int qs = 0; qs < 2; ++qs)
#pragma unroll
    for (int di = 0; di < 4; ++di)
#pragma unroll
      for (int r = 0; r < 4; ++r) {
        int s = q0 + qs * 16 + lhi * 4 + r;
        int d = di * 16 + llo;
        float val = o[qs][di][r] * linv[qs][r];
        aout[((size_t)b * 4096 + s) * 512 + h * 64 + d] = f2bf(val);
      }
}

// ---------------------------------------------------------------------------
// Output GEMM: out[8192][512] = attn_out @ w_out + b_out (fp32 out)
// 128x64 tiles, grid 64x8 = 512 blocks (2 blocks/CU, 2 waves/SIMD).
// 4 waves stacked on M (32 rows each); 2-phase double-buffered staging.
// ---------------------------------------------------------------------------
__global__ __launch_bounds__(256, 2) void out_gemm(
    const unsigned short* __restrict__ ab, const unsigned short* __restrict__ bt,
    const float* __restrict__ bias, float* __restrict__ out) {
  __shared__ unsigned short As[2][128 * 32];   // 8KB per buf
  __shared__ unsigned short Bs[2][64 * 32];    // 4KB per buf
  const int t = threadIdx.x;
  const int lane = t & 63;
  const int llo = lane & 15, lhi = lane >> 4;
  const int w = t >> 6;
  const int m0 = blockIdx.x * 128, n0 = blockIdx.y * 64;

  f32x4 acc[2][4];
#pragma unroll
  for (int i = 0; i < 2; ++i)
#pragma unroll
    for (int j = 0; j < 4; ++j) acc[i][j] = (f32x4){0.f, 0.f, 0.f, 0.f};

  const int r0 = t >> 2;
  const int sb = (t & 3) * 16;

  auto stage = [&](int k0, int buf) {
    const char* ga = (const char*)ab + (size_t)(m0 + r0) * 1024 + k0 * 2 + sb;
    const char* gb = (const char*)bt + (size_t)(n0 + r0) * 1024 + k0 * 2 + sb;
    load_lds16(ga, (char*)&As[buf][0] + t * 16);
    load_lds16(ga + 64 * 1024, (char*)&As[buf][0] + 4096 + t * 16);
    load_lds16(gb, (char*)&Bs[buf][0] + t * 16);
  };

  stage(0, 0);
  __syncthreads();

  int cur = 0;
  for (int k0 = 0; k0 < 512; k0 += 32) {
    if (k0 + 32 < 512) stage(k0 + 32, cur ^ 1);

    bf16x8 af[2], bf[4];
#pragma unroll
    for (int mi = 0; mi < 2; ++mi)
      af[mi] = *(const bf16x8*)(&As[cur][0] + (w * 32 + mi * 16 + llo) * 32 + lhi * 8);
#pragma unroll
    for (int ni = 0; ni < 4; ++ni)
      bf[ni] = *(const bf16x8*)(&Bs[cur][0] + (ni * 16 + llo) * 32 + lhi * 8);
#pragma unroll
    for (int mi = 0; mi < 2; ++mi)
#pragma unroll
      for (int ni = 0; ni < 4; ++ni)
        acc[mi][ni] = MFMA16(af[mi], bf[ni], acc[mi][ni], 0, 0, 0);
    __syncthreads();
    cur ^= 1;
  }

#pragma unroll
  for (int ni = 0; ni < 4; ++ni) {
    int col = n0 + ni * 16 + llo;
    float bv = bias[col];
#pragma unroll
    for (int mi = 0; mi < 2; ++mi) {
      int rowb = m0 + w * 32 + mi * 16 + lhi * 4;
#pragma unroll
      for (int r = 0; r < 4; ++r)
        out[(size_t)(rowb + r) * 512 + col] = acc[mi][ni][r] + bv;
    }
  }
}

// ---------------------------------------------------------------------------
extern "C" void kernel_launch(void* const* d_in, const int* in_sizes, int n_in,
                              void* d_out, int out_size, void* d_ws, size_t ws_size,
                              hipStream_t stream) {
  const float* x = (const float*)d_in[0];
  const float* wqkv = (const float*)d_in[1];
  const float* bqkv = (const float*)d_in[2];
  const float* wout = (const float*)d_in[3];
  const float* bout = (const float*)d_in[4];
  float* out = (float*)d_out;

  char* ws = (char*)d_ws;
  unsigned short* xb    = (unsigned short*)(ws + 0);         //  8,388,608 B
  unsigned short* wqkvT = (unsigned short*)(ws + 8388608);   //  1,572,864 B
  unsigned short* woutT = (unsigned short*)(ws + 9961472);   //    524,288 B
  unsigned short* qb    = (unsigned short*)(ws + 10485760);  //  8,388,608 B
  unsigned short* ksw   = (unsigned short*)(ws + 18874368);  //  8,388,608 B
  unsigned short* vtsw  = (unsigned short*)(ws + 27262976);  //  8,388,608 B
  unsigned short* ab    = (unsigned short*)(ws + 35651584);  //  8,388,608 B
  (void)ws_size; (void)in_sizes; (void)n_in; (void)out_size;

  prep_kernel<<<5120, 256, 0, stream>>>(x, wqkv, wout, xb, wqkvT, woutT);
  qkv_gemm<<<dim3(64, 12), 256, 0, stream>>>(xb, wqkvT, bqkv, qb, ksw, vtsw);
  attn_kernel<<<dim3(32, 16), 256, 0, stream>>>(qb, ksw, vtsw, ab);
  out_gemm<<<dim3(64, 8), 256, 0, stream>>>(ab, woutT, bout, out);
}